// Round 11
// baseline (237.375 us; speedup 1.0000x reference)
//
#include <hip/hip_runtime.h>
#include <math.h>

#define NREL 16
#define DE 64
#define DOUT 32
#define NPART 16
#define TQ 392

typedef __attribute__((ext_vector_type(8))) short bf16x8;
typedef __attribute__((ext_vector_type(16))) float f32x16;
typedef __attribute__((ext_vector_type(2))) float f32x2;

__device__ __forceinline__ short f2bf(float f) {
    unsigned u = __builtin_bit_cast(unsigned, f);
    unsigned r = (u + 0x7FFFu + ((u >> 16) & 1u)) >> 16;
    return (short)r;
}
__device__ __forceinline__ float bf2f(short s) {
    unsigned u = ((unsigned)(unsigned short)s) << 16;
    return __builtin_bit_cast(float, u);
}
__device__ __forceinline__ unsigned char f2fp8(float f) {
    int p = __builtin_amdgcn_cvt_pk_fp8_f32(f, f, 0, false);
    return (unsigned char)(p & 0xff);
}
__device__ __forceinline__ float tanh_fast(float x) {
    float e = __expf(2.0f * x);
    return fmaf(-2.0f, __builtin_amdgcn_rcpf(e + 1.0f), 1.0f);
}

// ---------------------------------------------------------------------------
// Fused: entcvt | wcvt | dst-partitioned hist (independent preprocessing)
__global__ __launch_bounds__(256) void prep_kernel(const float* __restrict__ ent,
                                                   short* __restrict__ entbf, int eTot,
                                                   const float* __restrict__ WR,
                                                   short* __restrict__ Wbf,
                                                   short* __restrict__ WTbf,
                                                   const int* __restrict__ dst,
                                                   int* __restrict__ counts,
                                                   int E, int psz,
                                                   int eB, int wB) {
    int b = blockIdx.x;
    if (b < eB) {
        int i = b * 256 + threadIdx.x;
        if (i < eTot) entbf[i] = f2bf(ent[i]);
    } else if (b < eB + wB) {
        int i = (b - eB) * 256 + threadIdx.x;
        int r = i >> 12, k = (i >> 6) & 63, j = i & 63;
        short w = f2bf(WR[i]);
        Wbf[i] = w;
        WTbf[(r << 12) + (j << 6) + k] = w;
    } else {
        int hb = b - eB - wB;
        int part = hb & (NPART - 1);
        int i = (hb / NPART) * 256 + threadIdx.x;
        if (i < E) {
            int d = dst[i];
            if (d >= part * psz && d < (part + 1) * psz)
                atomicAdd(&counts[d], 1);
        }
    }
}

// ---- 3-phase device-wide exclusive scan over counts[n] ----
__global__ __launch_bounds__(256) void blocksum_kernel(const int* __restrict__ counts,
                                                       int* __restrict__ blockSums, int n) {
    __shared__ int wsum[4];
    int i = blockIdx.x * 256 + threadIdx.x;
    int v = (i < n) ? counts[i] : 0;
#pragma unroll
    for (int off = 1; off < 64; off <<= 1) v += __shfl_xor(v, off);
    if ((threadIdx.x & 63) == 0) wsum[threadIdx.x >> 6] = v;
    __syncthreads();
    if (threadIdx.x == 0)
        blockSums[blockIdx.x] = wsum[0] + wsum[1] + wsum[2] + wsum[3];
}

__global__ __launch_bounds__(1024) void blockscan_kernel(int* __restrict__ blockSums, int nb) {
    __shared__ int lds[1024];
    int t = threadIdx.x;
    int v = (t < nb) ? blockSums[t] : 0;
    lds[t] = v;
    __syncthreads();
    for (int off = 1; off < 1024; off <<= 1) {
        int u = (t >= off) ? lds[t - off] : 0;
        __syncthreads();
        lds[t] += u;
        __syncthreads();
    }
    if (t < nb) blockSums[t] = (t == 0) ? 0 : lds[t - 1];   // exclusive
}

__global__ __launch_bounds__(256) void scanout_kernel(const int* __restrict__ counts,
                                                      const int* __restrict__ blockSums,
                                                      int* __restrict__ offsets,
                                                      int* __restrict__ cursor, int n) {
    __shared__ int wsum[4];
    int t = threadIdx.x;
    int i = blockIdx.x * 256 + t;
    int lane = t & 63;
    int w = t >> 6;
    int v = (i < n) ? counts[i] : 0;
    int incl = v;
#pragma unroll
    for (int off = 1; off < 64; off <<= 1) {
        int u = __shfl_up(incl, off);
        if (lane >= off) incl += u;
    }
    if (lane == 63) wsum[w] = incl;
    __syncthreads();
    int woff = 0;
#pragma unroll
    for (int j = 0; j < 4; ++j) if (j < w) woff += wsum[j];
    int excl = incl - v + woff + blockSums[blockIdx.x];
    if (i < n) { offsets[i] = excl; cursor[i] = excl; }
    if (i == n - 1) offsets[n] = excl + v;
}

// dst-range-partitioned scatter (standalone): partition slice of pks (~250KB)
// stays L2-resident so 4B stores merge before writeback.
__global__ __launch_bounds__(256) void scatter_kernel(const int* __restrict__ dst,
                                                      const int* __restrict__ src,
                                                      const int* __restrict__ etype,
                                                      int* __restrict__ cursor,
                                                      int* __restrict__ pks,
                                                      int E, int psz) {
    int part = blockIdx.x & (NPART - 1);
    int i = (blockIdx.x / NPART) * 256 + threadIdx.x;
    if (i < E) {
        int d = dst[i];
        if (d >= part * psz && d < (part + 1) * psz) {
            int pos = atomicAdd(&cursor[d], 1);
            pks[pos] = (src[i] << 4) | etype[i];
        }
    }
}

// ---------------------------------------------------------------------------
// MFMA projq: ONE relation per wave; lin = r*TQ + tq, TQ%8==0 -> XCD pinning.
// Qf8[r][node][k] = fp8(tanh(ent W_r + rel_r) W_r^T); nontemporal stores.
__global__ __launch_bounds__(256) void projq_kernel(const short* __restrict__ entbf,
                                                    const float* __restrict__ rel,
                                                    const short* __restrict__ Wbf,
                                                    const short* __restrict__ WTbf,
                                                    unsigned char* __restrict__ Qf8,
                                                    int N) {
    __shared__ short Tl[4 * 2048];   // per-wave tile (4KB), reused for fp8 repack
    int lane = threadIdx.x & 63;
    int wid = threadIdx.x >> 6;
    int lin = blockIdx.x;
    int r = lin / TQ;
    int tq = lin - r * TQ;
    int m0 = (tq * 4 + wid) * 32;
    if (m0 >= N) return;             // wave-uniform exit
    int hi = lane >> 5;
    int lo = lane & 31;

    int arow = m0 + lo;
    if (arow >= N) arow = N - 1;
    const short* ap = entbf + ((size_t)arow << 6) + hi * 8;
    bf16x8 A[4];
#pragma unroll
    for (int kk = 0; kk < 4; ++kk) A[kk] = *(const bf16x8*)(ap + kk * 16);

    short* tb = Tl + wid * 2048;
    const short* wtb = WTbf + ((size_t)r << 12);
    const short* wb  = Wbf  + ((size_t)r << 12);

    // GEMM1: P = ent @ W_r
    f32x16 acc0 = {}, acc1 = {};
#pragma unroll
    for (int kk = 0; kk < 4; ++kk) {
        bf16x8 b0 = *(const bf16x8*)(wtb + lo * DE + kk * 16 + hi * 8);
        bf16x8 b1 = *(const bf16x8*)(wtb + (lo + 32) * DE + kk * 16 + hi * 8);
        acc0 = __builtin_amdgcn_mfma_f32_32x32x16_bf16(A[kk], b0, acc0, 0, 0, 0);
        acc1 = __builtin_amdgcn_mfma_f32_32x32x16_bf16(A[kk], b1, acc1, 0, 0, 0);
    }
    // tanh(P + rel) -> bf16 -> swizzled LDS (C-layout -> A-layout)
    float rv0 = rel[r * DE + lo];
    float rv1 = rel[r * DE + 32 + lo];
#pragma unroll
    for (int i = 0; i < 16; ++i) {
        int row = (i & 3) + 8 * (i >> 2) + 4 * hi;
        int sw = (row & 7) << 3;
        tb[(row * DE + lo) ^ sw] = f2bf(tanh_fast(acc0[i] + rv0));
        tb[(row * DE + 32 + lo) ^ sw] = f2bf(tanh_fast(acc1[i] + rv1));
    }
    bf16x8 A2[4];
#pragma unroll
    for (int kk = 0; kk < 4; ++kk)
        A2[kk] = *(const bf16x8*)(tb + ((lo * DE + kk * 16 + hi * 8) ^ ((lo & 7) << 3)));

    // GEMM2: Qt = T @ W_r^T
    f32x16 q0 = {}, q1 = {};
#pragma unroll
    for (int kk = 0; kk < 4; ++kk) {
        bf16x8 b0 = *(const bf16x8*)(wb + lo * DE + kk * 16 + hi * 8);
        bf16x8 b1 = *(const bf16x8*)(wb + (lo + 32) * DE + kk * 16 + hi * 8);
        q0 = __builtin_amdgcn_mfma_f32_32x32x16_bf16(A2[kk], b0, q0, 0, 0, 0);
        q1 = __builtin_amdgcn_mfma_f32_32x32x16_bf16(A2[kk], b1, q1, 0, 0, 0);
    }
    // fp8 repack via LDS (reuse tb), then 512B-contiguous nontemporal stores
    unsigned char* tb8 = (unsigned char*)tb;
#pragma unroll
    for (int i = 0; i < 16; ++i) {
        int row = (i & 3) + 8 * (i >> 2) + 4 * hi;
        tb8[row * DE + lo] = f2fp8(q0[i]);
        tb8[row * DE + 32 + lo] = f2fp8(q1[i]);
    }
#pragma unroll
    for (int p = 0; p < 4; ++p) {
        int row = p * 8 + (lane >> 3);
        int node = m0 + row;
        unsigned long long vq = *(const unsigned long long*)(tb8 + row * DE + (lane & 7) * 8);
        if (node < N)
            __builtin_nontemporal_store(vq,
                (unsigned long long*)(Qf8 + (((size_t)r * N + node) << 6) + (lane & 7) * 8));
    }
}

// ---------------------------------------------------------------------------
// Fused agg: one wave per dst node; 8 edges in flight (8 lanes each),
// 2-deep pipeline (pks one iter ahead of gathers, gathers one ahead of use),
// per-group online softmax, 3-step merge, LDS-broadcast MLP. Q rows fp8.
__global__ __launch_bounds__(256) void agg_kernel(const float* __restrict__ ent,
                                                  const short* __restrict__ entbf,
                                                  const unsigned char* __restrict__ Qf8,
                                                  const int* __restrict__ offsets,
                                                  const int* __restrict__ pks,
                                                  const float* __restrict__ W1,
                                                  const float* __restrict__ b1,
                                                  const float* __restrict__ W2,
                                                  const float* __restrict__ b2,
                                                  float* __restrict__ out, int n) {
    __shared__ float xl[4][128];
    int lane = threadIdx.x & 63;
    int wid = threadIdx.x >> 6;
    int v = (blockIdx.x << 2) + wid;
    if (v >= n) return;
    int o0 = offsets[v], o1 = offsets[v + 1];
    int g = lane >> 3, gl = lane & 7;
    const unsigned char* qbase = Qf8 + ((size_t)v << 6) + gl * 8;  // +(r*n)<<6 per edge

    float m = -INFINITY, l = 0.f;
    float acc[8];
#pragma unroll
    for (int j = 0; j < 8; ++j) acc[j] = 0.f;

    int k = o0 + g;
    bool val = k < o1;
    bf16x8 xv = {};
    uint2 qv = {};
    if (val) {
        int pk = pks[k];
        xv = *(const bf16x8*)(entbf + ((size_t)(pk >> 4) << 6) + gl * 8);
        qv = *(const uint2*)(qbase + (((size_t)(pk & 15) * (size_t)n) << 6));
    }
    int kn = k + 8;
    bool valn = kn < o1;
    int pkn = valn ? pks[kn] : 0;

    int iters = (o1 - o0 + 7) >> 3;
    for (int it = 0; it < iters; ++it) {
        // issue gathers for next group (address already resolved)
        bf16x8 xn = {};
        uint2 qn = {};
        if (valn) {
            xn = *(const bf16x8*)(entbf + ((size_t)(pkn >> 4) << 6) + gl * 8);
            qn = *(const uint2*)(qbase + (((size_t)(pkn & 15) * (size_t)n) << 6));
        }
        // load index two groups ahead
        int kn2 = kn + 8;
        bool valn2 = kn2 < o1;
        int pkn2 = valn2 ? pks[kn2] : 0;

        // decode fp8 q (HW packed cvt) + att dot over 8 lanes
        f32x2 qa = __builtin_amdgcn_cvt_pk_f32_fp8(qv.x, false);
        f32x2 qb = __builtin_amdgcn_cvt_pk_f32_fp8(qv.x, true);
        f32x2 qc = __builtin_amdgcn_cvt_pk_f32_fp8(qv.y, false);
        f32x2 qd = __builtin_amdgcn_cvt_pk_f32_fp8(qv.y, true);
        float qf[8] = {qa[0], qa[1], qb[0], qb[1], qc[0], qc[1], qd[0], qd[1]};
        float xf[8];
        float d = 0.f;
#pragma unroll
        for (int j = 0; j < 8; ++j) {
            xf[j] = bf2f(xv[j]);
            d = fmaf(xf[j], qf[j], d);
        }
        d += __shfl_xor(d, 1);
        d += __shfl_xor(d, 2);
        d += __shfl_xor(d, 4);
        float p = val ? d : -INFINITY;
        // online softmax update (per group)
        float nm = fmaxf(m, p);
        float sc, pe;
        if (nm == -INFINITY) { sc = 0.f; pe = 0.f; }
        else { sc = __expf(m - nm); pe = __expf(p - nm); }
        l = l * sc + pe;
#pragma unroll
        for (int j = 0; j < 8; ++j) acc[j] = fmaf(acc[j], sc, pe * xf[j]);
        m = nm;
        // shift pipeline
        val = valn; xv = xn; qv = qn;
        kn = kn2; valn = valn2; pkn = pkn2;
    }
    // merge the 8 group-partials (group id = lane bits 3..5)
#pragma unroll
    for (int off = 8; off < 64; off <<= 1) {
        float mo = __shfl_xor(m, off);
        float lo2 = __shfl_xor(l, off);
        float nm = fmaxf(m, mo);
        float s1 = (nm == -INFINITY) ? 0.f : __expf(m - nm);
        float s2 = (nm == -INFINITY) ? 0.f : __expf(mo - nm);
        l = l * s1 + lo2 * s2;
#pragma unroll
        for (int j = 0; j < 8; ++j) {
            float ao = __shfl_xor(acc[j], off);
            acc[j] = acc[j] * s1 + ao * s2;
        }
        m = nm;
    }
    // redistribute Nh (feats gl*8..+7 per lane) -> lane=feat via LDS
    float* xw = &xl[wid][0];
    float invl = (l > 0.f) ? (1.0f / l) : 0.f;
    if (g == 0) {
#pragma unroll
        for (int j = 0; j < 8; ++j) xw[gl * 8 + j] = acc[j] * invl;
    }
    float node = ent[((size_t)v << 6) + lane];
    float Nh = xw[lane];                 // same-wave LDS RAW (compiler waits)
    float x1 = node + Nh;
    float x2 = node * Nh;
    xw[lane] = x1;
    xw[64 + lane] = x2;
    int j = lane & 31;
    const float* __restrict__ Wsel = (lane < 32) ? W1 : W2;
    float bias = (lane < 32) ? b1[j] : b2[j];
    const float* xb = xw + ((lane < 32) ? 0 : 64);
    float o = 0.f;
#pragma unroll 8
    for (int kk = 0; kk < DE; ++kk)
        o = fmaf(xb[kk], Wsel[kk * DOUT + j], o);
    o += bias;
    float lr = (o > 0.f) ? o : 0.01f * o;
    float other = __shfl_xor(lr, 32);
    if (lane < 32) out[(size_t)v * DOUT + lane] = lr + other;
}

// ---------------------------------------------------------------------------
extern "C" void kernel_launch(void* const* d_in, const int* in_sizes, int n_in,
                              void* d_out, int out_size, void* d_ws, size_t ws_size,
                              hipStream_t stream) {
    const float* ent = (const float*)d_in[0];
    const float* rel = (const float*)d_in[1];
    const float* WR  = (const float*)d_in[2];
    const float* W1  = (const float*)d_in[3];
    const float* b1  = (const float*)d_in[4];
    const float* W2  = (const float*)d_in[5];
    const float* b2  = (const float*)d_in[6];
    const int* src   = (const int*)d_in[7];
    const int* dst   = (const int*)d_in[8];
    const int* ety   = (const int*)d_in[9];
    float* out       = (float*)d_out;

    const int E = in_sizes[7];
    const int N = in_sizes[0] / DE;
    const int NB = (N + 255) / 256;             // scan partial blocks (<=1024)
    const int psz = (N + NPART - 1) / NPART;    // dst partition size
    const int chunks = (E + 255) / 256;

    size_t qBytes  = (size_t)N * NREL * DE;     // 51.2 MB fp8
    size_t eElems  = (size_t)N * DE;            // 3.2M bf16
    size_t wElems  = (size_t)NREL * DE * DE;    // 65536 bf16

    char* ws = (char*)d_ws;
    unsigned char* Qf8 = (unsigned char*)ws;
    short* entbf = (short*)(ws + qBytes);
    short* Wbf   = entbf + eElems;
    short* WTbf  = Wbf + wElems;
    int* counts  = (int*)(WTbf + wElems);
    int* offsets = counts + N;
    int* cursor  = offsets + N + 1;
    int* pks     = cursor + N;                  // E packed (src<<4|ety)
    int* bsums   = pks + E;                     // NB ints
    size_t need  = (size_t)((char*)(bsums + NB) - ws);
    if (ws_size < need) return;                 // ~63 MB needed

    const int eB = (int)((eElems + 255) / 256);
    const int wB = (int)(wElems / 256);

    hipMemsetAsync(counts, 0, (size_t)N * 4, stream);
    prep_kernel<<<eB + wB + chunks * NPART, 256, 0, stream>>>(
        ent, entbf, (int)eElems, WR, Wbf, WTbf, dst, counts, E, psz, eB, wB);
    blocksum_kernel<<<NB, 256, 0, stream>>>(counts, bsums, N);
    blockscan_kernel<<<1, 1024, 0, stream>>>(bsums, NB);
    scanout_kernel<<<NB, 256, 0, stream>>>(counts, bsums, offsets, cursor, N);
    scatter_kernel<<<chunks * NPART, 256, 0, stream>>>(dst, src, ety, cursor, pks, E, psz);
    projq_kernel<<<TQ * NREL, 256, 0, stream>>>(entbf, rel, Wbf, WTbf, Qf8, N);
    agg_kernel<<<(N + 3) / 4, 256, 0, stream>>>(ent, entbf, Qf8, offsets, pks,
                                                W1, b1, W2, b2, out, N);
}

// Round 12
// 219.046 us; speedup vs baseline: 1.0837x; 1.0837x over previous
//
#include <hip/hip_runtime.h>
#include <math.h>

#define NREL 16
#define DE 64
#define DOUT 32
#define NPART 16
#define TQ 392

typedef __attribute__((ext_vector_type(8))) short bf16x8;
typedef __attribute__((ext_vector_type(16))) float f32x16;
typedef __attribute__((ext_vector_type(2))) float f32x2;

__device__ __forceinline__ short f2bf(float f) {
    unsigned u = __builtin_bit_cast(unsigned, f);
    unsigned r = (u + 0x7FFFu + ((u >> 16) & 1u)) >> 16;
    return (short)r;
}
__device__ __forceinline__ float bf2f(short s) {
    unsigned u = ((unsigned)(unsigned short)s) << 16;
    return __builtin_bit_cast(float, u);
}
__device__ __forceinline__ unsigned char f2fp8(float f) {
    int p = __builtin_amdgcn_cvt_pk_fp8_f32(f, f, 0, false);
    return (unsigned char)(p & 0xff);
}
// packed f32x2 -> bf16x2 (1 instr; no builtin on gfx950)
__device__ __forceinline__ unsigned cvt_pk_bf16(float lo, float hi) {
    unsigned r;
    asm("v_cvt_pk_bf16_f32 %0, %1, %2" : "=v"(r) : "v"(lo), "v"(hi));
    return r;
}
__device__ __forceinline__ float tanh_fast(float x) {
    float e = __expf(2.0f * x);
    return fmaf(-2.0f, __builtin_amdgcn_rcpf(e + 1.0f), 1.0f);
}

// ---------------------------------------------------------------------------
// Fused: entcvt | wcvt (transpose only) | dst-partitioned hist
__global__ __launch_bounds__(256) void prep_kernel(const float* __restrict__ ent,
                                                   short* __restrict__ entbf, int eTot,
                                                   const float* __restrict__ WR,
                                                   short* __restrict__ WTbf,
                                                   const int* __restrict__ dst,
                                                   int* __restrict__ counts,
                                                   int E, int psz,
                                                   int eB, int wB) {
    int b = blockIdx.x;
    if (b < eB) {
        int i = b * 256 + threadIdx.x;
        if (i < eTot) entbf[i] = f2bf(ent[i]);
    } else if (b < eB + wB) {
        int i = (b - eB) * 256 + threadIdx.x;
        int r = i >> 12, k = (i >> 6) & 63, j = i & 63;
        WTbf[(r << 12) + (j << 6) + k] = f2bf(WR[i]);
    } else {
        int hb = b - eB - wB;
        int part = hb & (NPART - 1);
        int i = (hb / NPART) * 256 + threadIdx.x;
        if (i < E) {
            int d = dst[i];
            if (d >= part * psz && d < (part + 1) * psz)
                atomicAdd(&counts[d], 1);
        }
    }
}

// ---- 3-phase device-wide exclusive scan over counts[n] ----
__global__ __launch_bounds__(256) void blocksum_kernel(const int* __restrict__ counts,
                                                       int* __restrict__ blockSums, int n) {
    __shared__ int wsum[4];
    int i = blockIdx.x * 256 + threadIdx.x;
    int v = (i < n) ? counts[i] : 0;
#pragma unroll
    for (int off = 1; off < 64; off <<= 1) v += __shfl_xor(v, off);
    if ((threadIdx.x & 63) == 0) wsum[threadIdx.x >> 6] = v;
    __syncthreads();
    if (threadIdx.x == 0)
        blockSums[blockIdx.x] = wsum[0] + wsum[1] + wsum[2] + wsum[3];
}

__global__ __launch_bounds__(1024) void blockscan_kernel(int* __restrict__ blockSums, int nb) {
    __shared__ int lds[1024];
    int t = threadIdx.x;
    int v = (t < nb) ? blockSums[t] : 0;
    lds[t] = v;
    __syncthreads();
    for (int off = 1; off < 1024; off <<= 1) {
        int u = (t >= off) ? lds[t - off] : 0;
        __syncthreads();
        lds[t] += u;
        __syncthreads();
    }
    if (t < nb) blockSums[t] = (t == 0) ? 0 : lds[t - 1];   // exclusive
}

__global__ __launch_bounds__(256) void scanout_kernel(const int* __restrict__ counts,
                                                      const int* __restrict__ blockSums,
                                                      int* __restrict__ offsets,
                                                      int* __restrict__ cursor, int n) {
    __shared__ int wsum[4];
    int t = threadIdx.x;
    int i = blockIdx.x * 256 + t;
    int lane = t & 63;
    int w = t >> 6;
    int v = (i < n) ? counts[i] : 0;
    int incl = v;
#pragma unroll
    for (int off = 1; off < 64; off <<= 1) {
        int u = __shfl_up(incl, off);
        if (lane >= off) incl += u;
    }
    if (lane == 63) wsum[w] = incl;
    __syncthreads();
    int woff = 0;
#pragma unroll
    for (int j = 0; j < 4; ++j) if (j < w) woff += wsum[j];
    int excl = incl - v + woff + blockSums[blockIdx.x];
    if (i < n) { offsets[i] = excl; cursor[i] = excl; }
    if (i == n - 1) offsets[n] = excl + v;
}

// dst-range-partitioned scatter
__global__ __launch_bounds__(256) void scatter_kernel(const int* __restrict__ dst,
                                                      const int* __restrict__ src,
                                                      const int* __restrict__ etype,
                                                      int* __restrict__ cursor,
                                                      int* __restrict__ pks,
                                                      int E, int psz) {
    int part = blockIdx.x & (NPART - 1);
    int i = (blockIdx.x / NPART) * 256 + threadIdx.x;
    if (i < E) {
        int d = dst[i];
        if (d >= part * psz && d < (part + 1) * psz) {
            int pos = atomicAdd(&cursor[d], 1);
            pks[pos] = (src[i] << 4) | etype[i];
        }
    }
}

// ---------------------------------------------------------------------------
// MFMA projp: GEMM1 ONLY — Pf8[r][node][j] = fp8( ent[node] @ W_r )[j].
// No tanh, no GEMM2, no layout crossing. One relation per wave; TQ%8==0
// pins node-tile groups to one XCD across relations (ent L2-resident).
__global__ __launch_bounds__(256) void projp_kernel(const short* __restrict__ entbf,
                                                    const short* __restrict__ WTbf,
                                                    unsigned char* __restrict__ Pf8,
                                                    int N) {
    __shared__ short Tl[4 * 1024];   // per-wave 2KB fp8 repack tile
    int lane = threadIdx.x & 63;
    int wid = threadIdx.x >> 6;
    int lin = blockIdx.x;
    int r = lin / TQ;
    int tq = lin - r * TQ;
    int m0 = (tq * 4 + wid) * 32;
    if (m0 >= N) return;             // wave-uniform exit
    int hi = lane >> 5;
    int lo = lane & 31;

    int arow = m0 + lo;
    if (arow >= N) arow = N - 1;
    const short* ap = entbf + ((size_t)arow << 6) + hi * 8;
    bf16x8 A[4];
#pragma unroll
    for (int kk = 0; kk < 4; ++kk) A[kk] = *(const bf16x8*)(ap + kk * 16);

    const short* wtb = WTbf + ((size_t)r << 12);

    // P = ent @ W_r  (C-layout: lane holds col j=lo / j=lo+32, 16 rows)
    f32x16 acc0 = {}, acc1 = {};
#pragma unroll
    for (int kk = 0; kk < 4; ++kk) {
        bf16x8 b0 = *(const bf16x8*)(wtb + lo * DE + kk * 16 + hi * 8);
        bf16x8 b1 = *(const bf16x8*)(wtb + (lo + 32) * DE + kk * 16 + hi * 8);
        acc0 = __builtin_amdgcn_mfma_f32_32x32x16_bf16(A[kk], b0, acc0, 0, 0, 0);
        acc1 = __builtin_amdgcn_mfma_f32_32x32x16_bf16(A[kk], b1, acc1, 0, 0, 0);
    }
    // fp8 repack via per-wave LDS tile, then 512B-contiguous nt stores
    unsigned char* tb8 = (unsigned char*)(Tl + wid * 1024);
#pragma unroll
    for (int i = 0; i < 16; ++i) {
        int row = (i & 3) + 8 * (i >> 2) + 4 * hi;
        tb8[row * DE + lo] = f2fp8(acc0[i]);
        tb8[row * DE + 32 + lo] = f2fp8(acc1[i]);
    }
#pragma unroll
    for (int p = 0; p < 4; ++p) {
        int row = p * 8 + (lane >> 3);
        int node = m0 + row;
        unsigned long long vq = *(const unsigned long long*)(tb8 + row * DE + (lane & 7) * 8);
        if (node < N)
            __builtin_nontemporal_store(vq,
                (unsigned long long*)(Pf8 + (((size_t)r * N + node) << 6) + (lane & 7) * 8));
    }
}

// ---------------------------------------------------------------------------
// Fused agg. Phase 0 (per dst node): t[r][j] = tanh(P[r][v][j] + rel[r][j])
// for all 16 r into 2KB LDS (amortized over the node's edges).
// Edge loop: att = P[r][src] . t[r]  (h fp8 gather 8B/lane + LDS t read);
// 8 edges in flight, 2-deep pipeline, online softmax, merge, LDS-bcast MLP.
__global__ __launch_bounds__(256) void agg_kernel(const float* __restrict__ ent,
                                                  const short* __restrict__ entbf,
                                                  const unsigned char* __restrict__ Pf8,
                                                  const float* __restrict__ rel,
                                                  const int* __restrict__ offsets,
                                                  const int* __restrict__ pks,
                                                  const float* __restrict__ W1,
                                                  const float* __restrict__ b1,
                                                  const float* __restrict__ W2,
                                                  const float* __restrict__ b2,
                                                  float* __restrict__ out, int n) {
    __shared__ float xl[4][128];
    __shared__ short tl[4][NREL * DE];   // 4 waves x 2KB bf16 t-tables
    int lane = threadIdx.x & 63;
    int wid = threadIdx.x >> 6;
    int v = (blockIdx.x << 2) + wid;
    if (v >= n) return;
    int o0 = offsets[v], o1 = offsets[v + 1];
    int g = lane >> 3, gl = lane & 7;

    // ---- phase 0: per-node t-table (same-wave produce/consume, no barrier)
    short* tw = &tl[wid][0];
    const unsigned char* pv = Pf8 + ((size_t)v << 6);
#pragma unroll
    for (int pass = 0; pass < 4; ++pass) {
        int r = pass * 4 + (lane >> 4);
        int j4 = (lane & 15) * 4;
        unsigned pj = *(const unsigned*)(pv + (((size_t)r * (unsigned)n) << 6) + j4);
        f32x2 pa = __builtin_amdgcn_cvt_pk_f32_fp8(pj, false);
        f32x2 pb = __builtin_amdgcn_cvt_pk_f32_fp8(pj, true);
        float4 rv = *(const float4*)(rel + r * DE + j4);
        unsigned lo32 = cvt_pk_bf16(tanh_fast(pa[0] + rv.x), tanh_fast(pa[1] + rv.y));
        unsigned hi32 = cvt_pk_bf16(tanh_fast(pb[0] + rv.z), tanh_fast(pb[1] + rv.w));
        *(uint2*)(&tw[r * DE + j4]) = make_uint2(lo32, hi32);
    }

    float m = -INFINITY, l = 0.f;
    float acc[8];
#pragma unroll
    for (int j = 0; j < 8; ++j) acc[j] = 0.f;

    int k = o0 + g;
    bool val = k < o1;
    bf16x8 xv = {};
    uint2 hv = {};
    int rcur = 0;
    if (val) {
        int pk = pks[k];
        rcur = pk & 15;
        unsigned idx = (unsigned)rcur * (unsigned)n + (unsigned)(pk >> 4);
        xv = *(const bf16x8*)(entbf + ((size_t)(pk >> 4) << 6) + gl * 8);
        hv = *(const uint2*)(Pf8 + ((size_t)idx << 6) + gl * 8);
    }
    int kn = k + 8;
    bool valn = kn < o1;
    int pkn = valn ? pks[kn] : 0;

    int iters = (o1 - o0 + 7) >> 3;
    for (int it = 0; it < iters; ++it) {
        // issue gathers for next group (address already resolved)
        bf16x8 xn = {};
        uint2 hn = {};
        int rnext = pkn & 15;
        if (valn) {
            unsigned idx = (unsigned)rnext * (unsigned)n + (unsigned)(pkn >> 4);
            xn = *(const bf16x8*)(entbf + ((size_t)(pkn >> 4) << 6) + gl * 8);
            hn = *(const uint2*)(Pf8 + ((size_t)idx << 6) + gl * 8);
        }
        // index two groups ahead
        int kn2 = kn + 8;
        bool valn2 = kn2 < o1;
        int pkn2 = valn2 ? pks[kn2] : 0;

        // t row from LDS, h fp8 decode, dot over 8 lanes
        bf16x8 tt = *(const bf16x8*)(&tw[rcur * DE + gl * 8]);
        f32x2 ha = __builtin_amdgcn_cvt_pk_f32_fp8(hv.x, false);
        f32x2 hb = __builtin_amdgcn_cvt_pk_f32_fp8(hv.x, true);
        f32x2 hc = __builtin_amdgcn_cvt_pk_f32_fp8(hv.y, false);
        f32x2 hd = __builtin_amdgcn_cvt_pk_f32_fp8(hv.y, true);
        float hf[8] = {ha[0], ha[1], hb[0], hb[1], hc[0], hc[1], hd[0], hd[1]};
        float xf[8];
        float d = 0.f;
#pragma unroll
        for (int j = 0; j < 8; ++j) {
            xf[j] = bf2f(xv[j]);
            d = fmaf(hf[j], bf2f(tt[j]), d);
        }
        d += __shfl_xor(d, 1);
        d += __shfl_xor(d, 2);
        d += __shfl_xor(d, 4);
        float p = val ? d : -INFINITY;
        // online softmax update (per group)
        float nm = fmaxf(m, p);
        float sc, pe;
        if (nm == -INFINITY) { sc = 0.f; pe = 0.f; }
        else { sc = __expf(m - nm); pe = __expf(p - nm); }
        l = l * sc + pe;
#pragma unroll
        for (int j = 0; j < 8; ++j) acc[j] = fmaf(acc[j], sc, pe * xf[j]);
        m = nm;
        // shift pipeline
        val = valn; xv = xn; hv = hn; rcur = rnext;
        kn = kn2; valn = valn2; pkn = pkn2;
    }
    // merge the 8 group-partials
#pragma unroll
    for (int off = 8; off < 64; off <<= 1) {
        float mo = __shfl_xor(m, off);
        float lo2 = __shfl_xor(l, off);
        float nm = fmaxf(m, mo);
        float s1 = (nm == -INFINITY) ? 0.f : __expf(m - nm);
        float s2 = (nm == -INFINITY) ? 0.f : __expf(mo - nm);
        l = l * s1 + lo2 * s2;
#pragma unroll
        for (int j = 0; j < 8; ++j) {
            float ao = __shfl_xor(acc[j], off);
            acc[j] = acc[j] * s1 + ao * s2;
        }
        m = nm;
    }
    // redistribute Nh -> lane=feat via LDS
    float* xw = &xl[wid][0];
    float invl = (l > 0.f) ? (1.0f / l) : 0.f;
    if (g == 0) {
#pragma unroll
        for (int j = 0; j < 8; ++j) xw[gl * 8 + j] = acc[j] * invl;
    }
    float node = ent[((size_t)v << 6) + lane];
    float Nh = xw[lane];                 // same-wave LDS RAW
    float x1 = node + Nh;
    float x2 = node * Nh;
    xw[lane] = x1;
    xw[64 + lane] = x2;
    int j = lane & 31;
    const float* __restrict__ Wsel = (lane < 32) ? W1 : W2;
    float bias = (lane < 32) ? b1[j] : b2[j];
    const float* xb = xw + ((lane < 32) ? 0 : 64);
    float o = 0.f;
#pragma unroll 8
    for (int kk = 0; kk < DE; ++kk)
        o = fmaf(xb[kk], Wsel[kk * DOUT + j], o);
    o += bias;
    float lr = (o > 0.f) ? o : 0.01f * o;
    float other = __shfl_xor(lr, 32);
    if (lane < 32) out[(size_t)v * DOUT + lane] = lr + other;
}

// ---------------------------------------------------------------------------
extern "C" void kernel_launch(void* const* d_in, const int* in_sizes, int n_in,
                              void* d_out, int out_size, void* d_ws, size_t ws_size,
                              hipStream_t stream) {
    const float* ent = (const float*)d_in[0];
    const float* rel = (const float*)d_in[1];
    const float* WR  = (const float*)d_in[2];
    const float* W1  = (const float*)d_in[3];
    const float* b1  = (const float*)d_in[4];
    const float* W2  = (const float*)d_in[5];
    const float* b2  = (const float*)d_in[6];
    const int* src   = (const int*)d_in[7];
    const int* dst   = (const int*)d_in[8];
    const int* ety   = (const int*)d_in[9];
    float* out       = (float*)d_out;

    const int E = in_sizes[7];
    const int N = in_sizes[0] / DE;
    const int NB = (N + 255) / 256;             // scan partial blocks (<=1024)
    const int psz = (N + NPART - 1) / NPART;    // dst partition size
    const int chunks = (E + 255) / 256;

    size_t pBytes  = (size_t)N * NREL * DE;     // 51.2 MB fp8 P table
    size_t eElems  = (size_t)N * DE;            // 3.2M bf16
    size_t wElems  = (size_t)NREL * DE * DE;    // 65536 bf16

    char* ws = (char*)d_ws;
    unsigned char* Pf8 = (unsigned char*)ws;
    short* entbf = (short*)(ws + pBytes);
    short* WTbf  = entbf + eElems;
    int* counts  = (int*)(WTbf + wElems);
    int* offsets = counts + N;
    int* cursor  = offsets + N + 1;
    int* pks     = cursor + N;                  // E packed (src<<4|ety)
    int* bsums   = pks + E;                     // NB ints
    size_t need  = (size_t)((char*)(bsums + NB) - ws);
    if (ws_size < need) return;                 // ~63 MB needed

    const int eB = (int)((eElems + 255) / 256);
    const int wB = (int)(wElems / 256);

    hipMemsetAsync(counts, 0, (size_t)N * 4, stream);
    prep_kernel<<<eB + wB + chunks * NPART, 256, 0, stream>>>(
        ent, entbf, (int)eElems, WR, WTbf, dst, counts, E, psz, eB, wB);
    blocksum_kernel<<<NB, 256, 0, stream>>>(counts, bsums, N);
    blockscan_kernel<<<1, 1024, 0, stream>>>(bsums, NB);
    scanout_kernel<<<NB, 256, 0, stream>>>(counts, bsums, offsets, cursor, N);
    scatter_kernel<<<chunks * NPART, 256, 0, stream>>>(dst, src, ety, cursor, pks, E, psz);
    projp_kernel<<<TQ * NREL, 256, 0, stream>>>(entbf, WTbf, Pf8, N);
    agg_kernel<<<(N + 3) / 4, 256, 0, stream>>>(ent, entbf, Pf8, rel, offsets, pks,
                                                W1, b1, W2, b2, out, N);
}